// Round 5
// baseline (393.481 us; speedup 1.0000x reference)
//
#include <hip/hip_runtime.h>
#include <hip/hip_bf16.h>

typedef unsigned short u16;
typedef float f32x4 __attribute__((ext_vector_type(4)));
typedef short s16x8 __attribute__((ext_vector_type(8)));

__device__ __forceinline__ u16 f2b(float f) {
    union { float f; unsigned u; } c; c.f = f;
    unsigned r = c.u + 0x7fffu + ((c.u >> 16) & 1u);
    return (u16)(r >> 16);
}
// packed f32x2 -> bf16x2 (v_cvt_pk_bf16_f32 on gfx950); low16 = a, high16 = b
__device__ __forceinline__ unsigned pkbf16(float a, float b) {
    union { __hip_bfloat162 h; unsigned u; } c;
    c.h = __float22bfloat162_rn(float2{a, b});
    return c.u;
}

// async global->LDS, 16B per lane; LDS dst = base + lane*16 (wave-uniform base)
#define ASYNC_COPY16(gp, lp)                                                       \
    __builtin_amdgcn_global_load_lds(                                              \
        (const __attribute__((address_space(1))) void*)(gp),                       \
        (__attribute__((address_space(3))) void*)(lp), 16, 0, 0)

// ---------------------------------------------------------------------------
// Weight cast+transpose body: W (K x N) f32 -> Wt (N x K) bf16, 64x64 tile.
// permute=1 interleaves gate/up channel rows (for fused-silu epilogue).
// ---------------------------------------------------------------------------
__device__ __forceinline__ void transcast_body(const float* __restrict__ Wz,
                                               u16* __restrict__ Wtz,
                                               int K, int N, int bx, int by,
                                               int permute) {
    __shared__ float tile[64][65];
    const int n0 = bx * 64, k0 = by * 64;
    const int tid = threadIdx.x;
    const int tx = tid & 15, ty = tid >> 4;
#pragma unroll
    for (int it = 0; it < 4; it++) {
        int r = ty + it * 16;
        float4 v = *(const float4*)&Wz[(size_t)(k0 + r) * N + n0 + tx * 4];
        tile[r][tx * 4 + 0] = v.x;
        tile[r][tx * 4 + 1] = v.y;
        tile[r][tx * 4 + 2] = v.z;
        tile[r][tx * 4 + 3] = v.w;
    }
    __syncthreads();
    int n = tid >> 2;
    int ks = (tid & 3) * 16;
    int drow = n0 + n;
    if (permute) drow = (drow < 1024) ? 2 * drow : 2 * (drow - 1024) + 1;
    u16* dst = &Wtz[(size_t)drow * K + k0 + ks];
#pragma unroll
    for (int h = 0; h < 2; h++) {
        uint4 o;
        o.x = pkbf16(tile[ks + h * 8 + 0][n], tile[ks + h * 8 + 1][n]);
        o.y = pkbf16(tile[ks + h * 8 + 2][n], tile[ks + h * 8 + 3][n]);
        o.z = pkbf16(tile[ks + h * 8 + 4][n], tile[ks + h * 8 + 5][n]);
        o.w = pkbf16(tile[ks + h * 8 + 6][n], tile[ks + h * 8 + 7][n]);
        *(uint4*)(dst + h * 8) = o;
    }
}

// f32 -> bf16 cast body, 8 elems/thread, one block-slice
__device__ __forceinline__ void cast_body(const float* __restrict__ x,
                                          u16* __restrict__ y, int blk) {
    int id = blk * 256 + threadIdx.x;
    const float* p = x + (size_t)id * 8;
    float4 a = *(const float4*)p;
    float4 b = *(const float4*)(p + 4);
    uint4 o;
    o.x = pkbf16(a.x, a.y);
    o.y = pkbf16(a.z, a.w);
    o.z = pkbf16(b.x, b.y);
    o.w = pkbf16(b.z, b.w);
    *(uint4*)(y + (size_t)id * 8) = o;
}

// LayerNorm body over H=1024; pack=1: MoE expert-packed row order
__device__ __forceinline__ void ln_body(const float* __restrict__ x,
                                        const float* __restrict__ g,
                                        const float* __restrict__ bb,
                                        u16* __restrict__ out, int token, int pack) {
    int tid = threadIdx.x;
    const float* row = x + (size_t)token * 1024;
    float4 v = *(const float4*)(row + tid * 4);
    float s1 = v.x + v.y + v.z + v.w;
    float s2 = v.x * v.x + v.y * v.y + v.z * v.z + v.w * v.w;
#pragma unroll
    for (int off = 32; off > 0; off >>= 1) {
        s1 += __shfl_down(s1, off);
        s2 += __shfl_down(s2, off);
    }
    __shared__ float ws1[4], ws2[4];
    int wave = tid >> 6;
    if ((tid & 63) == 0) { ws1[wave] = s1; ws2[wave] = s2; }
    __syncthreads();
    float t1 = ws1[0] + ws1[1] + ws1[2] + ws1[3];
    float t2 = ws2[0] + ws2[1] + ws2[2] + ws2[3];
    float mean = t1 * (1.f / 1024.f);
    float var = t2 * (1.f / 1024.f) - mean * mean;
    float rstd = rsqrtf(var + 1e-6f);
    size_t dest = token;
    if (pack) {
        int bq = token >> 10, q = token & 1023;
        dest = (size_t)(q & 3) * 1024 + (size_t)bq * 256 + (q >> 2);
    }
    int c = tid * 4;
    float4 gv = *(const float4*)(g + c);
    float4 bv = *(const float4*)(bb + c);
    uint2 o;
    o.x = pkbf16((v.x - mean) * rstd * gv.x + bv.x, (v.y - mean) * rstd * gv.y + bv.y);
    o.y = pkbf16((v.z - mean) * rstd * gv.z + bv.z, (v.w - mean) * rstd * gv.w + bv.w);
    *(uint2*)&out[dest * 1024 + c] = o;
}

__global__ __launch_bounds__(256) void ln_kernel(const float* __restrict__ x,
                                                 const float* __restrict__ g,
                                                 const float* __restrict__ bb,
                                                 u16* __restrict__ out, int pack) {
    ln_body(x, g, bb, out, blockIdx.x, pack);
}

// ---------------------------------------------------------------------------
// Mega prep kernel: all input-independent prep in ONE launch (was 5 launches —
// same-stream kernels serialize fully, so each separate launch paid ramp+tail).
// Block ranges: [0,1024) 4 square-weight transcasts; [1024,3072) gate_up
// transcast (permuted); [3072,4096) down transcast; [4096,8192) kv f32->bf16
// cast; [8192,12288) LN1.
// ---------------------------------------------------------------------------
__global__ __launch_bounds__(256) void prep_kernel(
    const float* __restrict__ Wq, const float* __restrict__ Wk,
    const float* __restrict__ Wv, const float* __restrict__ Wo,
    u16* __restrict__ wqt, u16* __restrict__ wkt,
    u16* __restrict__ wvt, u16* __restrict__ wot,
    const float* __restrict__ gate_up, u16* __restrict__ gut,
    const float* __restrict__ down, u16* __restrict__ dnt,
    const float* __restrict__ key_value, u16* __restrict__ kvbf,
    const float* __restrict__ query, const float* __restrict__ g1,
    const float* __restrict__ b1, u16* __restrict__ xn) {
    const int idx = blockIdx.x;
    if (idx < 1024) {
        int z = idx >> 8, r = idx & 255;
        const float* W = (z == 0) ? Wq : (z == 1) ? Wk : (z == 2) ? Wv : Wo;
        u16* O = (z == 0) ? wqt : (z == 1) ? wkt : (z == 2) ? wvt : wot;
        transcast_body(W, O, 1024, 1024, r >> 4, r & 15, 0);
    } else if (idx < 3072) {
        int t = idx - 1024, z = t >> 9, r = t & 511;
        transcast_body(gate_up + (size_t)z * 2097152, gut + (size_t)z * 2097152,
                       1024, 2048, r >> 4, r & 15, 1);
    } else if (idx < 4096) {
        int t = idx - 3072, z = t >> 8, r = t & 255;
        transcast_body(down + (size_t)z * 1048576, dnt + (size_t)z * 1048576,
                       1024, 1024, r >> 4, r & 15, 0);
    } else if (idx < 8192) {
        cast_body(key_value, kvbf, idx - 4096);
    } else {
        ln_body(query, g1, b1, xn, idx - 8192, 0);
    }
}

// ---------------------------------------------------------------------------
// bf16 MFMA GEMM body, BK=64, XOR seg-swizzle, LDS via global_load_lds
// (R7: removing LDS is 2.2x slower). Dynamic-LDS so multiple tile shapes can
// share one kernel. mode: 0=normal (outF+resid | outH*outScale), 1=MoE scatter
// f32+resid, 2=silu-pair -> outH (N/2 ch), 3=K normal + V in flash pi-fragment
// layout (outH2). R14: BM=64 grids restored (R13's BM=128 grids hit 1 blk/CU
// -> occupancy/tail regression, total +37us).
// ---------------------------------------------------------------------------
template <int BM>
__device__ __forceinline__ void gemm_body(
    u16* As, u16* Bs,
    const u16* __restrict__ Ab, const u16* __restrict__ Bb,
    const float* __restrict__ bias0, const float* __restrict__ bias1, int biasSplit,
    const float* __restrict__ resid,
    float* __restrict__ outF, u16* __restrict__ outH, u16* __restrict__ outH2,
    int N, int K, long long oStride, int z, int mode, float outScale,
    int m0, int n0) {
    constexpr int NJ = (BM == 128) ? 4 : 2;
    const int tid = threadIdx.x;
    const int wave = tid >> 6, lane = tid & 63;
    const int wm = (BM == 128) ? (wave >> 1) * 64 : 0;
    const int wn = (BM == 128) ? (wave & 1) * 64 : wave * 32;
    const int quad = lane >> 4, l16 = lane & 15;
    f32x4 acc[4][NJ] = {};
    for (int k0 = 0; k0 < K; k0 += 64) {
#pragma unroll
        for (int i = 0; i < BM / 32; i++) {
            int id = tid + i * 256;
            int row = id >> 3, c = id & 7;
            int srcseg = c ^ (row & 7);
            ASYNC_COPY16(&Ab[(size_t)(m0 + row) * K + k0 + srcseg * 8],
                         As + (size_t)(wave * 64 + i * 256) * 8);
        }
#pragma unroll
        for (int i = 0; i < 4; i++) {
            int id = tid + i * 256;
            int row = id >> 3, c = id & 7;
            int srcseg = c ^ (row & 7);
            ASYNC_COPY16(&Bb[(size_t)(n0 + row) * K + k0 + srcseg * 8],
                         Bs + (size_t)(wave * 64 + i * 256) * 8);
        }
        __syncthreads();
#pragma unroll
        for (int kk = 0; kk < 2; kk++) {
            s16x8 af[4], bfr[NJ];
#pragma unroll
            for (int i = 0; i < 4; i++) {
                int row = wm + i * 16 + l16;
                af[i] = *(const s16x8*)&As[row * 64 + ((kk * 4 + quad) ^ (row & 7)) * 8];
            }
#pragma unroll
            for (int j = 0; j < NJ; j++) {
                int row = wn + j * 16 + l16;
                bfr[j] = *(const s16x8*)&Bs[row * 64 + ((kk * 4 + quad) ^ (row & 7)) * 8];
            }
#pragma unroll
            for (int i = 0; i < 4; i++)
#pragma unroll
                for (int j = 0; j < NJ; j++)
                    acc[i][j] = __builtin_amdgcn_mfma_f32_16x16x32_bf16(af[i], bfr[j], acc[i][j], 0, 0, 0);
        }
        __syncthreads();
    }
#pragma unroll
    for (int i = 0; i < 4; i++) {
#pragma unroll
        for (int j = 0; j < NJ; j++) {
            int col = n0 + wn + j * 16 + l16;
            float bv = 0.f;
            if (bias0) bv = (col < biasSplit) ? bias0[col] : bias1[col - biasSplit];
            if (mode == 3) {
                float vr[4];
#pragma unroll
                for (int r = 0; r < 4; r++) vr[r] = acc[i][j][r] + bv;
                int row0 = m0 + wm + i * 16 + quad * 4;
                if (col < 1024) {
#pragma unroll
                    for (int r = 0; r < 4; r++)
                        outH[(size_t)(row0 + r) * 1024 + col] = f2b(vr[r]);
                } else {
                    // flash pi-fragment scatter: key kk within chunk cc lands at
                    // seg = ((kk4>>1)*4 + q4) ^ (d&7), half = kk4&1
                    int bb2 = row0 >> 11, key = row0 & 2047;
                    int hh = (col - 1024) >> 6, d = (col - 1024) & 63;
                    int cc = key >> 6, kk = key & 63;
                    int kk4 = kk >> 4, q4 = (kk >> 2) & 3;
                    int seg = (((kk4 >> 1) << 2) | q4) ^ (d & 7);
                    int half = kk4 & 1;
                    uint2 dw;
                    dw.x = pkbf16(vr[0], vr[1]);
                    dw.y = pkbf16(vr[2], vr[3]);
                    *(uint2*)&outH2[((((size_t)bb2 * 16 + hh) * 32 + cc) * 64 + d) * 64
                                    + seg * 8 + half * 4] = dw;
                }
                continue;
            }
#pragma unroll
            for (int r = 0; r < 4; r++) {
                int row = m0 + wm + i * 16 + quad * 4 + r;
                float v = acc[i][j][r] + bv;
                if (mode == 2) {
                    float other = __shfl_xor(v, 1);
                    if (!(lane & 1)) {
                        float res = (v / (1.f + __expf(-v))) * other;
                        outH[(size_t)z * oStride + (size_t)row * (N >> 1) + (col >> 1)] = f2b(res);
                    }
                } else if (mode == 1) {
                    int bb2 = row >> 8, qi = row & 255;
                    size_t oidx = ((size_t)bb2 * 1024 + (size_t)z + 4 * (size_t)qi) * N + col;
                    outF[oidx] = v + resid[oidx];
                } else {
                    size_t oidx = (size_t)z * oStride + (size_t)row * N + col;
                    if (resid) v += resid[oidx];
                    if (outF) outF[oidx] = v;
                    else outH[oidx] = f2b(v * outScale);
                }
            }
        }
    }
}

// standalone GEMM wrapper (3-D grid, hardware dispatch order — R5 lesson)
template <int BM>
__global__ __launch_bounds__(256) void gemm_t(
    const u16* __restrict__ A, const u16* __restrict__ Bt,
    const float* __restrict__ bias0, const float* __restrict__ bias1, int biasSplit,
    const float* __restrict__ resid,
    float* __restrict__ outF, u16* __restrict__ outH, u16* __restrict__ outH2,
    int N, int K,
    long long aStride, long long bStride, long long oStride,
    int mode, float outScale) {
    extern __shared__ __align__(16) u16 ldsb[];
    const int z = blockIdx.z;
    gemm_body<BM>(ldsb, ldsb + BM * 64,
                  A + (size_t)z * aStride, Bt + (size_t)z * bStride,
                  bias0, bias1, biasSplit, resid, outF, outH, outH2,
                  N, K, oStride, z, mode, outScale,
                  blockIdx.y * BM, blockIdx.x * 128);
}

// ---------------------------------------------------------------------------
// Merged Q-proj + KV-proj. R14: XCD-aware logical remap — measured 106 MB
// FETCH vs ~47 MB unique input: the 16 blocks sharing one A-panel landed
// round-robin on 8 XCDs, each XCD's L2 re-fetching the panel. Remap so each
// XCD (bid&7) owns 8 consecutive by-panels: A read once from HBM, only B
// (4 MB) duplicated per XCD.
// ---------------------------------------------------------------------------
__global__ __launch_bounds__(256) void gemm_qkv(
    const u16* __restrict__ xn, const u16* __restrict__ wqt,
    const float* __restrict__ bq,
    const u16* __restrict__ kvbf, const u16* __restrict__ kvw,
    const float* __restrict__ bk, const float* __restrict__ bv,
    u16* __restrict__ qb, u16* __restrict__ kvb, u16* __restrict__ vtb,
    float qscale) {
    extern __shared__ __align__(16) u16 ldsb[];
    const int bid = blockIdx.x;
    if (bid < 1024) {           // KV: xcd owns by in [xcd*8, xcd*8+8)
        int xcd = bid & 7, slot = bid >> 3;
        int by = xcd * 8 + (slot >> 4), bx = slot & 15;
        gemm_body<128>(ldsb, ldsb + 128 * 64, kvbf, kvw,
                       bk, bv, 1024, nullptr, nullptr, kvb, vtb,
                       2048, 1024, 0, 0, 3, 1.f,
                       by * 128, bx * 128);
    } else {                    // Q: xcd owns by in [xcd*8, xcd*8+8)
        int t = bid - 1024;
        int xcd = t & 7, slot = t >> 3;
        int by = xcd * 8 + (slot >> 3), bx = slot & 7;
        gemm_body<64>(ldsb, ldsb + 64 * 64, xn, wqt,
                      bq, bq, 1 << 30, nullptr, nullptr, qb, nullptr,
                      1024, 1024, 0, 0, 0, qscale,
                      by * 64, bx * 128);
    }
}

// ---------------------------------------------------------------------------
// Flash attention v10: v9 structure + R15 change: register-resident loop
// invariants. v9 compiled to 36 VGPRs (launch_bounds(512) made the compiler
// minimize registers for occupancy we can't use — grid 512 = 2 blocks/CU =
// 4 waves/SIMD, so <=128 VGPRs is free). At 36 VGPRs it recomputed all 24
// swizzled LDS addresses + 64-bit staging addresses every chunk (~300 VALU
// instrs/chunk measured vs ~60 irreducible). Fix: __launch_bounds__(512,4)
// (VGPR cap 128, matches resident occupancy) + explicit hoisting: 16
// precomputed uint4-indices (XOR swizzle collapses to l16&7), running global
// src pointers, fixed per-buffer LDS dst pointers.
// ---------------------------------------------------------------------------
__global__ __launch_bounds__(512, 4) void flash_attn(
    const u16* __restrict__ Q, const u16* __restrict__ Kb,
    const u16* __restrict__ VT, u16* __restrict__ O) {
    const int lidx = blockIdx.x;               // 512 blocks
    const int xcd = lidx & 7, slot = lidx >> 3;
    const int g = xcd + 8 * (slot >> 3);       // (b,h) group, 0..63
    const int qt = slot & 7;
    const int b = g >> 4, h = g & 15;
    const int tid = threadIdx.x, wave = tid >> 6, lane = tid & 63;
    const int quad = lane >> 4, l16 = lane & 15;
    const int q0 = qt * 128 + wave * 16;

    __shared__ __align__(16) u16 Ks[2][64 * 64];   // [key][d], 8-seg swz
    __shared__ __align__(16) u16 Vs[2][64 * 64];   // [d][pi(key)], 8-seg swz

    const size_t qrow = ((size_t)b * 1024 + q0 + l16) * 1024 + (size_t)h * 64;
    s16x8 qf0 = *(const s16x8*)&Q[qrow + quad * 8];
    s16x8 qf1 = *(const s16x8*)&Q[qrow + 32 + quad * 8];

    f32x4 o[4] = {};
    float l = 0.f;

    // ---- loop-invariant LDS uint4-indices (row&7 == l16&7 for all rows) ----
    const int l7 = l16 & 7;
    int koff[4][2], voff[2][4];
#pragma unroll
    for (int kt = 0; kt < 4; kt++) {
        koff[kt][0] = (kt * 16 + l16) * 8 + (quad ^ l7);
        koff[kt][1] = (kt * 16 + l16) * 8 + ((4 + quad) ^ l7);
    }
#pragma unroll
    for (int c2 = 0; c2 < 2; c2++)
#pragma unroll
        for (int dt = 0; dt < 4; dt++)
            voff[c2][dt] = (dt * 16 + l16) * 8 + ((c2 * 4 + quad) ^ l7);

    // ---- running staging pointers (one add per chunk, no c-multiplies) ----
    const int krow = tid >> 3;                 // key within chunk
    const int ksrcseg = (tid & 7) ^ (krow & 7);
    const u16* kSrc = Kb + ((size_t)b * 2048) * 1024 + (size_t)h * 64
                        + (size_t)krow * 1024 + ksrcseg * 8;
    const u16* vSrc = VT + ((size_t)(b * 16 + h) * 32) * 4096 + (size_t)tid * 8;
    u16* const kDst0 = &Ks[0][(size_t)(wave * 64) * 8];
    u16* const kDst1 = &Ks[1][(size_t)(wave * 64) * 8];
    u16* const vDst0 = &Vs[0][(size_t)(wave * 64) * 8];
    u16* const vDst1 = &Vs[1][(size_t)(wave * 64) * 8];

    ASYNC_COPY16(kSrc, kDst0);
    ASYNC_COPY16(vSrc, vDst0);
    kSrc += 64 * 1024; vSrc += 4096;

    for (int c = 0; c < 32; c++) {
        __syncthreads();                        // stage(c) landed; other buf free
        if (c < 31) {                           // prefetch next chunk
            if (c & 1) { ASYNC_COPY16(kSrc, kDst0); ASYNC_COPY16(vSrc, vDst0); }
            else       { ASYNC_COPY16(kSrc, kDst1); ASYNC_COPY16(vSrc, vDst1); }
            kSrc += 64 * 1024; vSrc += 4096;
        }
        const uint4* Kp = (const uint4*)((c & 1) ? &Ks[1][0] : &Ks[0][0]);
        const uint4* Vp = (const uint4*)((c & 1) ? &Vs[1][0] : &Vs[0][0]);

        f32x4 s[4];
#pragma unroll
        for (int kt = 0; kt < 4; kt++) {
            union { uint4 v; s16x8 f; } a0, a1;
            a0.v = Kp[koff[kt][0]];
            a1.v = Kp[koff[kt][1]];
            f32x4 acc = {};
            acc = __builtin_amdgcn_mfma_f32_16x16x32_bf16(a0.f, qf0, acc, 0, 0, 0);
            s[kt] = __builtin_amdgcn_mfma_f32_16x16x32_bf16(a1.f, qf1, acc, 0, 0, 0);
        }

        uint2 dw[4];
        float rs = 0.f;
#pragma unroll
        for (int kt = 0; kt < 4; kt++) {
            float p0 = exp2f(s[kt][0]), p1 = exp2f(s[kt][1]);
            float p2 = exp2f(s[kt][2]), p3 = exp2f(s[kt][3]);
            rs += (p0 + p1) + (p2 + p3);
            dw[kt].x = pkbf16(p0, p1);
            dw[kt].y = pkbf16(p2, p3);
        }
        l += rs;

#pragma unroll
        for (int c2 = 0; c2 < 2; c2++) {
            union { uint4 v; s16x8 f; } pf;
            pf.v = uint4{dw[2 * c2].x, dw[2 * c2].y, dw[2 * c2 + 1].x, dw[2 * c2 + 1].y};
#pragma unroll
            for (int dt = 0; dt < 4; dt++) {
                union { uint4 v; s16x8 f; } vf;
                vf.v = Vp[voff[c2][dt]];
                o[dt] = __builtin_amdgcn_mfma_f32_16x16x32_bf16(vf.f, pf.f, o[dt], 0, 0, 0);
            }
        }
    }

    l += __shfl_xor(l, 16);
    l += __shfl_xor(l, 32);
    float inv = 1.f / l;
#pragma unroll
    for (int dt = 0; dt < 4; dt++) {
        uint2 dw;
        dw.x = pkbf16(o[dt][0] * inv, o[dt][1] * inv);
        dw.y = pkbf16(o[dt][2] * inv, o[dt][3] * inv);
        *(uint2*)&O[qrow + dt * 16 + quad * 4] = dw;
    }
}

// ---------------------------------------------------------------------------
extern "C" void kernel_launch(void* const* d_in, const int* in_sizes, int n_in,
                              void* d_out, int out_size, void* d_ws, size_t ws_size,
                              hipStream_t stream) {
    (void)in_sizes; (void)n_in; (void)out_size; (void)ws_size;
    const float* query     = (const float*)d_in[0];
    const float* key_value = (const float*)d_in[1];
    const float* Wq = (const float*)d_in[2];
    const float* bq = (const float*)d_in[3];
    const float* Wk = (const float*)d_in[4];
    const float* bk = (const float*)d_in[5];
    const float* Wv = (const float*)d_in[6];
    const float* bv = (const float*)d_in[7];
    const float* Wo = (const float*)d_in[8];
    const float* bo = (const float*)d_in[9];
    const float* g1 = (const float*)d_in[10];
    const float* b1 = (const float*)d_in[11];
    const float* g2 = (const float*)d_in[12];
    const float* b2 = (const float*)d_in[13];
    const float* gate_up = (const float*)d_in[14];
    const float* down    = (const float*)d_in[15];
    float* out = (float*)d_out;

    char* wsb = (char*)d_ws;
    size_t off = 0;
    auto alloc = [&](size_t bytes) {
        char* p = wsb + off;
        off += (bytes + 255) & ~(size_t)255;
        return (void*)p;
    };
    u16* buf8a = (u16*)alloc((size_t)4096 * 1024 * 2);      // xn / ctx / hp
    u16* qb    = (u16*)alloc((size_t)4096 * 1024 * 2);
    u16* kvb   = (u16*)alloc((size_t)8192 * 1024 * 2);      // K proj out [b][key][1024]
    u16* vtb   = (u16*)alloc((size_t)8192 * 1024 * 2);      // V pi-fragment layout
    u16* kvbf  = (u16*)alloc((size_t)8192 * 1024 * 2);      // bf16 key_value; later inter
    float* x2  = (float*)alloc((size_t)4096 * 1024 * 4);
    u16* wqt   = (u16*)alloc((size_t)1024 * 1024 * 2);
    u16* kvw   = (u16*)alloc((size_t)2048 * 1024 * 2);      // Wk^T | Wv^T stacked
    u16* wot   = (u16*)alloc((size_t)1024 * 1024 * 2);
    u16* gut   = (u16*)alloc((size_t)4 * 2048 * 1024 * 2);  // permuted gate/up
    u16* dnt   = (u16*)alloc((size_t)4 * 1024 * 1024 * 2);
    u16* xn = buf8a; u16* ctx = buf8a; u16* hp = buf8a;
    u16* inter = kvbf;  // kvbf dead after KV projection
    const int BIG = 1 << 30;
    const float QSCALE = 0.125f * 1.44269504f;  // fold 1/sqrt(d) and log2(e)

    // all prep (weight transcasts + kv cast + LN1) in one launch
    prep_kernel<<<12288, 256, 0, stream>>>(
        Wq, Wk, Wv, Wo, wqt, kvw, kvw + (size_t)1024 * 1024, wot,
        gate_up, gut, down, dnt, key_value, kvbf, query, g1, b1, xn);
    // Q proj + KV proj merged (Q pre-scaled for exp2 softmax; KV mode 3)
    gemm_qkv<<<1536, 256, 32768, stream>>>(xn, wqt, bq, kvbf, kvw, bk, bv,
                                           qb, kvb, vtb, QSCALE);
    flash_attn<<<512, 512, 0, stream>>>(qb, kvb, vtb, ctx);
    // x2 = query + ctx@Wo + bo
    gemm_t<64><<<dim3(8, 64, 1), 256, 24576, stream>>>(ctx, wot, bo, bo, BIG,
        query, x2, nullptr, nullptr, 1024, 1024, 0, 0, 0, 0, 1.f);
    ln_kernel<<<4096, 256, 0, stream>>>(x2, g2, b2, hp, 1);
    // MoE gate_up + fused SiLU
    gemm_t<64><<<dim3(16, 16, 4), 256, 24576, stream>>>(hp, gut, nullptr, nullptr, BIG,
        nullptr, nullptr, inter, nullptr, 2048, 1024,
        (long long)1024 * 1024, (long long)2048 * 1024, (long long)1024 * 1024, 2, 1.f);
    // down-proj + residual + unscatter -> d_out
    gemm_t<64><<<dim3(8, 16, 4), 256, 24576, stream>>>(inter, dnt, nullptr, nullptr, BIG,
        x2, out, nullptr, nullptr, 1024, 1024,
        (long long)1024 * 1024, (long long)1024 * 1024, 0, 1, 1.f);
}

// Round 6
// 371.610 us; speedup vs baseline: 1.0589x; 1.0589x over previous
//
#include <hip/hip_runtime.h>
#include <hip/hip_bf16.h>

typedef unsigned short u16;
typedef float f32x4 __attribute__((ext_vector_type(4)));
typedef short s16x8 __attribute__((ext_vector_type(8)));

__device__ __forceinline__ u16 f2b(float f) {
    union { float f; unsigned u; } c; c.f = f;
    unsigned r = c.u + 0x7fffu + ((c.u >> 16) & 1u);
    return (u16)(r >> 16);
}
// packed f32x2 -> bf16x2 (v_cvt_pk_bf16_f32 on gfx950); low16 = a, high16 = b
__device__ __forceinline__ unsigned pkbf16(float a, float b) {
    union { __hip_bfloat162 h; unsigned u; } c;
    c.h = __float22bfloat162_rn(float2{a, b});
    return c.u;
}

// async global->LDS, 16B per lane; LDS dst = base + lane*16 (wave-uniform base)
#define ASYNC_COPY16(gp, lp)                                                       \
    __builtin_amdgcn_global_load_lds(                                              \
        (const __attribute__((address_space(1))) void*)(gp),                       \
        (__attribute__((address_space(3))) void*)(lp), 16, 0, 0)

// ---------------------------------------------------------------------------
// Weight cast+transpose body: W (K x N) f32 -> Wt (N x K) bf16, 64x64 tile.
// permute=1 interleaves gate/up channel rows (for fused-silu epilogue).
// ---------------------------------------------------------------------------
__device__ __forceinline__ void transcast_body(const float* __restrict__ Wz,
                                               u16* __restrict__ Wtz,
                                               int K, int N, int bx, int by,
                                               int permute) {
    __shared__ float tile[64][65];
    const int n0 = bx * 64, k0 = by * 64;
    const int tid = threadIdx.x;
    const int tx = tid & 15, ty = tid >> 4;
#pragma unroll
    for (int it = 0; it < 4; it++) {
        int r = ty + it * 16;
        float4 v = *(const float4*)&Wz[(size_t)(k0 + r) * N + n0 + tx * 4];
        tile[r][tx * 4 + 0] = v.x;
        tile[r][tx * 4 + 1] = v.y;
        tile[r][tx * 4 + 2] = v.z;
        tile[r][tx * 4 + 3] = v.w;
    }
    __syncthreads();
    int n = tid >> 2;
    int ks = (tid & 3) * 16;
    int drow = n0 + n;
    if (permute) drow = (drow < 1024) ? 2 * drow : 2 * (drow - 1024) + 1;
    u16* dst = &Wtz[(size_t)drow * K + k0 + ks];
#pragma unroll
    for (int h = 0; h < 2; h++) {
        uint4 o;
        o.x = pkbf16(tile[ks + h * 8 + 0][n], tile[ks + h * 8 + 1][n]);
        o.y = pkbf16(tile[ks + h * 8 + 2][n], tile[ks + h * 8 + 3][n]);
        o.z = pkbf16(tile[ks + h * 8 + 4][n], tile[ks + h * 8 + 5][n]);
        o.w = pkbf16(tile[ks + h * 8 + 6][n], tile[ks + h * 8 + 7][n]);
        *(uint4*)(dst + h * 8) = o;
    }
}

// f32 -> bf16 cast body, 8 elems/thread, one block-slice
__device__ __forceinline__ void cast_body(const float* __restrict__ x,
                                          u16* __restrict__ y, int blk) {
    int id = blk * 256 + threadIdx.x;
    const float* p = x + (size_t)id * 8;
    float4 a = *(const float4*)p;
    float4 b = *(const float4*)(p + 4);
    uint4 o;
    o.x = pkbf16(a.x, a.y);
    o.y = pkbf16(a.z, a.w);
    o.z = pkbf16(b.x, b.y);
    o.w = pkbf16(b.z, b.w);
    *(uint4*)(y + (size_t)id * 8) = o;
}

// LayerNorm body over H=1024; pack=1: MoE expert-packed row order
__device__ __forceinline__ void ln_body(const float* __restrict__ x,
                                        const float* __restrict__ g,
                                        const float* __restrict__ bb,
                                        u16* __restrict__ out, int token, int pack) {
    int tid = threadIdx.x;
    const float* row = x + (size_t)token * 1024;
    float4 v = *(const float4*)(row + tid * 4);
    float s1 = v.x + v.y + v.z + v.w;
    float s2 = v.x * v.x + v.y * v.y + v.z * v.z + v.w * v.w;
#pragma unroll
    for (int off = 32; off > 0; off >>= 1) {
        s1 += __shfl_down(s1, off);
        s2 += __shfl_down(s2, off);
    }
    __shared__ float ws1[4], ws2[4];
    int wave = tid >> 6;
    if ((tid & 63) == 0) { ws1[wave] = s1; ws2[wave] = s2; }
    __syncthreads();
    float t1 = ws1[0] + ws1[1] + ws1[2] + ws1[3];
    float t2 = ws2[0] + ws2[1] + ws2[2] + ws2[3];
    float mean = t1 * (1.f / 1024.f);
    float var = t2 * (1.f / 1024.f) - mean * mean;
    float rstd = rsqrtf(var + 1e-6f);
    size_t dest = token;
    if (pack) {
        int bq = token >> 10, q = token & 1023;
        dest = (size_t)(q & 3) * 1024 + (size_t)bq * 256 + (q >> 2);
    }
    int c = tid * 4;
    float4 gv = *(const float4*)(g + c);
    float4 bv = *(const float4*)(bb + c);
    uint2 o;
    o.x = pkbf16((v.x - mean) * rstd * gv.x + bv.x, (v.y - mean) * rstd * gv.y + bv.y);
    o.y = pkbf16((v.z - mean) * rstd * gv.z + bv.z, (v.w - mean) * rstd * gv.w + bv.w);
    *(uint2*)&out[dest * 1024 + c] = o;
}

__global__ __launch_bounds__(256) void ln_kernel(const float* __restrict__ x,
                                                 const float* __restrict__ g,
                                                 const float* __restrict__ bb,
                                                 u16* __restrict__ out, int pack) {
    ln_body(x, g, bb, out, blockIdx.x, pack);
}

// ---------------------------------------------------------------------------
// Mega prep kernel: all input-independent prep in ONE launch (was 5 launches —
// same-stream kernels serialize fully, so each separate launch paid ramp+tail).
// Block ranges: [0,1024) 4 square-weight transcasts; [1024,3072) gate_up
// transcast (permuted); [3072,4096) down transcast; [4096,8192) kv f32->bf16
// cast; [8192,12288) LN1.
// ---------------------------------------------------------------------------
__global__ __launch_bounds__(256) void prep_kernel(
    const float* __restrict__ Wq, const float* __restrict__ Wk,
    const float* __restrict__ Wv, const float* __restrict__ Wo,
    u16* __restrict__ wqt, u16* __restrict__ wkt,
    u16* __restrict__ wvt, u16* __restrict__ wot,
    const float* __restrict__ gate_up, u16* __restrict__ gut,
    const float* __restrict__ down, u16* __restrict__ dnt,
    const float* __restrict__ key_value, u16* __restrict__ kvbf,
    const float* __restrict__ query, const float* __restrict__ g1,
    const float* __restrict__ b1, u16* __restrict__ xn) {
    const int idx = blockIdx.x;
    if (idx < 1024) {
        int z = idx >> 8, r = idx & 255;
        const float* W = (z == 0) ? Wq : (z == 1) ? Wk : (z == 2) ? Wv : Wo;
        u16* O = (z == 0) ? wqt : (z == 1) ? wkt : (z == 2) ? wvt : wot;
        transcast_body(W, O, 1024, 1024, r >> 4, r & 15, 0);
    } else if (idx < 3072) {
        int t = idx - 1024, z = t >> 9, r = t & 511;
        transcast_body(gate_up + (size_t)z * 2097152, gut + (size_t)z * 2097152,
                       1024, 2048, r >> 4, r & 15, 1);
    } else if (idx < 4096) {
        int t = idx - 3072, z = t >> 8, r = t & 255;
        transcast_body(down + (size_t)z * 1048576, dnt + (size_t)z * 1048576,
                       1024, 1024, r >> 4, r & 15, 0);
    } else if (idx < 8192) {
        cast_body(key_value, kvbf, idx - 4096);
    } else {
        ln_body(query, g1, b1, xn, idx - 8192, 0);
    }
}

// ---------------------------------------------------------------------------
// bf16 MFMA GEMM body, BK=64, XOR seg-swizzle, LDS via global_load_lds
// (R7: removing LDS is 2.2x slower). Dynamic-LDS so multiple tile shapes can
// share one kernel. mode: 0=normal (outF+resid | outH*outScale), 1=MoE scatter
// f32+resid, 2=silu-pair -> outH (N/2 ch), 3=K normal + V in flash pi-fragment
// layout (outH2). R14: BM=64 grids restored (R13's BM=128 grids hit 1 blk/CU
// -> occupancy/tail regression, total +37us).
// ---------------------------------------------------------------------------
template <int BM>
__device__ __forceinline__ void gemm_body(
    u16* As, u16* Bs,
    const u16* __restrict__ Ab, const u16* __restrict__ Bb,
    const float* __restrict__ bias0, const float* __restrict__ bias1, int biasSplit,
    const float* __restrict__ resid,
    float* __restrict__ outF, u16* __restrict__ outH, u16* __restrict__ outH2,
    int N, int K, long long oStride, int z, int mode, float outScale,
    int m0, int n0) {
    constexpr int NJ = (BM == 128) ? 4 : 2;
    const int tid = threadIdx.x;
    const int wave = tid >> 6, lane = tid & 63;
    const int wm = (BM == 128) ? (wave >> 1) * 64 : 0;
    const int wn = (BM == 128) ? (wave & 1) * 64 : wave * 32;
    const int quad = lane >> 4, l16 = lane & 15;
    f32x4 acc[4][NJ] = {};
    for (int k0 = 0; k0 < K; k0 += 64) {
#pragma unroll
        for (int i = 0; i < BM / 32; i++) {
            int id = tid + i * 256;
            int row = id >> 3, c = id & 7;
            int srcseg = c ^ (row & 7);
            ASYNC_COPY16(&Ab[(size_t)(m0 + row) * K + k0 + srcseg * 8],
                         As + (size_t)(wave * 64 + i * 256) * 8);
        }
#pragma unroll
        for (int i = 0; i < 4; i++) {
            int id = tid + i * 256;
            int row = id >> 3, c = id & 7;
            int srcseg = c ^ (row & 7);
            ASYNC_COPY16(&Bb[(size_t)(n0 + row) * K + k0 + srcseg * 8],
                         Bs + (size_t)(wave * 64 + i * 256) * 8);
        }
        __syncthreads();
#pragma unroll
        for (int kk = 0; kk < 2; kk++) {
            s16x8 af[4], bfr[NJ];
#pragma unroll
            for (int i = 0; i < 4; i++) {
                int row = wm + i * 16 + l16;
                af[i] = *(const s16x8*)&As[row * 64 + ((kk * 4 + quad) ^ (row & 7)) * 8];
            }
#pragma unroll
            for (int j = 0; j < NJ; j++) {
                int row = wn + j * 16 + l16;
                bfr[j] = *(const s16x8*)&Bs[row * 64 + ((kk * 4 + quad) ^ (row & 7)) * 8];
            }
#pragma unroll
            for (int i = 0; i < 4; i++)
#pragma unroll
                for (int j = 0; j < NJ; j++)
                    acc[i][j] = __builtin_amdgcn_mfma_f32_16x16x32_bf16(af[i], bfr[j], acc[i][j], 0, 0, 0);
        }
        __syncthreads();
    }
#pragma unroll
    for (int i = 0; i < 4; i++) {
#pragma unroll
        for (int j = 0; j < NJ; j++) {
            int col = n0 + wn + j * 16 + l16;
            float bv = 0.f;
            if (bias0) bv = (col < biasSplit) ? bias0[col] : bias1[col - biasSplit];
            if (mode == 3) {
                float vr[4];
#pragma unroll
                for (int r = 0; r < 4; r++) vr[r] = acc[i][j][r] + bv;
                int row0 = m0 + wm + i * 16 + quad * 4;
                if (col < 1024) {
#pragma unroll
                    for (int r = 0; r < 4; r++)
                        outH[(size_t)(row0 + r) * 1024 + col] = f2b(vr[r]);
                } else {
                    // flash pi-fragment scatter: key kk within chunk cc lands at
                    // seg = ((kk4>>1)*4 + q4) ^ (d&7), half = kk4&1
                    int bb2 = row0 >> 11, key = row0 & 2047;
                    int hh = (col - 1024) >> 6, d = (col - 1024) & 63;
                    int cc = key >> 6, kk = key & 63;
                    int kk4 = kk >> 4, q4 = (kk >> 2) & 3;
                    int seg = (((kk4 >> 1) << 2) | q4) ^ (d & 7);
                    int half = kk4 & 1;
                    uint2 dw;
                    dw.x = pkbf16(vr[0], vr[1]);
                    dw.y = pkbf16(vr[2], vr[3]);
                    *(uint2*)&outH2[((((size_t)bb2 * 16 + hh) * 32 + cc) * 64 + d) * 64
                                    + seg * 8 + half * 4] = dw;
                }
                continue;
            }
#pragma unroll
            for (int r = 0; r < 4; r++) {
                int row = m0 + wm + i * 16 + quad * 4 + r;
                float v = acc[i][j][r] + bv;
                if (mode == 2) {
                    float other = __shfl_xor(v, 1);
                    if (!(lane & 1)) {
                        float res = (v / (1.f + __expf(-v))) * other;
                        outH[(size_t)z * oStride + (size_t)row * (N >> 1) + (col >> 1)] = f2b(res);
                    }
                } else if (mode == 1) {
                    int bb2 = row >> 8, qi = row & 255;
                    size_t oidx = ((size_t)bb2 * 1024 + (size_t)z + 4 * (size_t)qi) * N + col;
                    outF[oidx] = v + resid[oidx];
                } else {
                    size_t oidx = (size_t)z * oStride + (size_t)row * N + col;
                    if (resid) v += resid[oidx];
                    if (outF) outF[oidx] = v;
                    else outH[oidx] = f2b(v * outScale);
                }
            }
        }
    }
}

// standalone GEMM wrapper (3-D grid, hardware dispatch order — R5 lesson)
template <int BM>
__global__ __launch_bounds__(256) void gemm_t(
    const u16* __restrict__ A, const u16* __restrict__ Bt,
    const float* __restrict__ bias0, const float* __restrict__ bias1, int biasSplit,
    const float* __restrict__ resid,
    float* __restrict__ outF, u16* __restrict__ outH, u16* __restrict__ outH2,
    int N, int K,
    long long aStride, long long bStride, long long oStride,
    int mode, float outScale) {
    extern __shared__ __align__(16) u16 ldsb[];
    const int z = blockIdx.z;
    gemm_body<BM>(ldsb, ldsb + BM * 64,
                  A + (size_t)z * aStride, Bt + (size_t)z * bStride,
                  bias0, bias1, biasSplit, resid, outF, outH, outH2,
                  N, K, oStride, z, mode, outScale,
                  blockIdx.y * BM, blockIdx.x * 128);
}

// ---------------------------------------------------------------------------
// Merged Q-proj + KV-proj. R14: XCD-aware logical remap — measured 106 MB
// FETCH vs ~47 MB unique input: the 16 blocks sharing one A-panel landed
// round-robin on 8 XCDs, each XCD's L2 re-fetching the panel. Remap so each
// XCD (bid&7) owns 8 consecutive by-panels: A read once from HBM, only B
// (4 MB) duplicated per XCD.
// ---------------------------------------------------------------------------
__global__ __launch_bounds__(256) void gemm_qkv(
    const u16* __restrict__ xn, const u16* __restrict__ wqt,
    const float* __restrict__ bq,
    const u16* __restrict__ kvbf, const u16* __restrict__ kvw,
    const float* __restrict__ bk, const float* __restrict__ bv,
    u16* __restrict__ qb, u16* __restrict__ kvb, u16* __restrict__ vtb,
    float qscale) {
    extern __shared__ __align__(16) u16 ldsb[];
    const int bid = blockIdx.x;
    if (bid < 1024) {           // KV: xcd owns by in [xcd*8, xcd*8+8)
        int xcd = bid & 7, slot = bid >> 3;
        int by = xcd * 8 + (slot >> 4), bx = slot & 15;
        gemm_body<128>(ldsb, ldsb + 128 * 64, kvbf, kvw,
                       bk, bv, 1024, nullptr, nullptr, kvb, vtb,
                       2048, 1024, 0, 0, 3, 1.f,
                       by * 128, bx * 128);
    } else {                    // Q: xcd owns by in [xcd*8, xcd*8+8)
        int t = bid - 1024;
        int xcd = t & 7, slot = t >> 3;
        int by = xcd * 8 + (slot >> 3), bx = slot & 7;
        gemm_body<64>(ldsb, ldsb + 64 * 64, xn, wqt,
                      bq, bq, 1 << 30, nullptr, nullptr, qb, nullptr,
                      1024, 1024, 0, 0, 0, qscale,
                      by * 64, bx * 128);
    }
}

// ---------------------------------------------------------------------------
// Flash attention v11: v10 structure + R16 changes:
// (1) exp2f -> __builtin_amdgcn_exp2f. Theory: VALUBusy 53% = ~375 VALU
//     instrs/wave/chunk vs ~60 in source; without -ffast-math hipcc lowers
//     exp2f through OCML with range-guard code (~10x expansion). Scores are
//     bounded (Q pre-scaled 0.125*log2e), bare v_exp_f32 is exact there.
// (2) preload c2=0 V-fragments (4 x ds_read_b128, +16 VGPR) before softmax
//     so their LDS latency hides under it; c2=1 stays inline under c2=0 MFMAs.
// ---------------------------------------------------------------------------
__global__ __launch_bounds__(512, 4) void flash_attn(
    const u16* __restrict__ Q, const u16* __restrict__ Kb,
    const u16* __restrict__ VT, u16* __restrict__ O) {
    const int lidx = blockIdx.x;               // 512 blocks
    const int xcd = lidx & 7, slot = lidx >> 3;
    const int g = xcd + 8 * (slot >> 3);       // (b,h) group, 0..63
    const int qt = slot & 7;
    const int b = g >> 4, h = g & 15;
    const int tid = threadIdx.x, wave = tid >> 6, lane = tid & 63;
    const int quad = lane >> 4, l16 = lane & 15;
    const int q0 = qt * 128 + wave * 16;

    __shared__ __align__(16) u16 Ks[2][64 * 64];   // [key][d], 8-seg swz
    __shared__ __align__(16) u16 Vs[2][64 * 64];   // [d][pi(key)], 8-seg swz

    const size_t qrow = ((size_t)b * 1024 + q0 + l16) * 1024 + (size_t)h * 64;
    s16x8 qf0 = *(const s16x8*)&Q[qrow + quad * 8];
    s16x8 qf1 = *(const s16x8*)&Q[qrow + 32 + quad * 8];

    f32x4 o[4] = {};
    float l = 0.f;

    // ---- loop-invariant LDS uint4-indices (row&7 == l16&7 for all rows) ----
    const int l7 = l16 & 7;
    int koff[4][2], voff[2][4];
#pragma unroll
    for (int kt = 0; kt < 4; kt++) {
        koff[kt][0] = (kt * 16 + l16) * 8 + (quad ^ l7);
        koff[kt][1] = (kt * 16 + l16) * 8 + ((4 + quad) ^ l7);
    }
#pragma unroll
    for (int c2 = 0; c2 < 2; c2++)
#pragma unroll
        for (int dt = 0; dt < 4; dt++)
            voff[c2][dt] = (dt * 16 + l16) * 8 + ((c2 * 4 + quad) ^ l7);

    // ---- running staging pointers (one add per chunk, no c-multiplies) ----
    const int krow = tid >> 3;                 // key within chunk
    const int ksrcseg = (tid & 7) ^ (krow & 7);
    const u16* kSrc = Kb + ((size_t)b * 2048) * 1024 + (size_t)h * 64
                        + (size_t)krow * 1024 + ksrcseg * 8;
    const u16* vSrc = VT + ((size_t)(b * 16 + h) * 32) * 4096 + (size_t)tid * 8;
    u16* const kDst0 = &Ks[0][(size_t)(wave * 64) * 8];
    u16* const kDst1 = &Ks[1][(size_t)(wave * 64) * 8];
    u16* const vDst0 = &Vs[0][(size_t)(wave * 64) * 8];
    u16* const vDst1 = &Vs[1][(size_t)(wave * 64) * 8];

    ASYNC_COPY16(kSrc, kDst0);
    ASYNC_COPY16(vSrc, vDst0);
    kSrc += 64 * 1024; vSrc += 4096;

    for (int c = 0; c < 32; c++) {
        __syncthreads();                        // stage(c) landed; other buf free
        if (c < 31) {                           // prefetch next chunk
            if (c & 1) { ASYNC_COPY16(kSrc, kDst0); ASYNC_COPY16(vSrc, vDst0); }
            else       { ASYNC_COPY16(kSrc, kDst1); ASYNC_COPY16(vSrc, vDst1); }
            kSrc += 64 * 1024; vSrc += 4096;
        }
        const uint4* Kp = (const uint4*)((c & 1) ? &Ks[1][0] : &Ks[0][0]);
        const uint4* Vp = (const uint4*)((c & 1) ? &Vs[1][0] : &Vs[0][0]);

        f32x4 s[4];
#pragma unroll
        for (int kt = 0; kt < 4; kt++) {
            union { uint4 v; s16x8 f; } a0, a1;
            a0.v = Kp[koff[kt][0]];
            a1.v = Kp[koff[kt][1]];
            f32x4 acc = {};
            acc = __builtin_amdgcn_mfma_f32_16x16x32_bf16(a0.f, qf0, acc, 0, 0, 0);
            s[kt] = __builtin_amdgcn_mfma_f32_16x16x32_bf16(a1.f, qf1, acc, 0, 0, 0);
        }

        // preload c2=0 V-fragments; LDS latency overlaps the softmax below
        union { uint4 v; s16x8 f; } vf0[4];
#pragma unroll
        for (int dt = 0; dt < 4; dt++) vf0[dt].v = Vp[voff[0][dt]];

        uint2 dw[4];
        float rs = 0.f;
#pragma unroll
        for (int kt = 0; kt < 4; kt++) {
            float p0 = __builtin_amdgcn_exp2f(s[kt][0]);
            float p1 = __builtin_amdgcn_exp2f(s[kt][1]);
            float p2 = __builtin_amdgcn_exp2f(s[kt][2]);
            float p3 = __builtin_amdgcn_exp2f(s[kt][3]);
            rs += (p0 + p1) + (p2 + p3);
            dw[kt].x = pkbf16(p0, p1);
            dw[kt].y = pkbf16(p2, p3);
        }
        l += rs;

        // PV: c2=0 from preloaded regs, c2=1 inline (latency under c2=0 MFMAs)
        union { uint4 v; s16x8 f; } pf0, pf1;
        pf0.v = uint4{dw[0].x, dw[0].y, dw[1].x, dw[1].y};
        pf1.v = uint4{dw[2].x, dw[2].y, dw[3].x, dw[3].y};
        union { uint4 v; s16x8 f; } vf1[4];
#pragma unroll
        for (int dt = 0; dt < 4; dt++) vf1[dt].v = Vp[voff[1][dt]];
#pragma unroll
        for (int dt = 0; dt < 4; dt++)
            o[dt] = __builtin_amdgcn_mfma_f32_16x16x32_bf16(vf0[dt].f, pf0.f, o[dt], 0, 0, 0);
#pragma unroll
        for (int dt = 0; dt < 4; dt++)
            o[dt] = __builtin_amdgcn_mfma_f32_16x16x32_bf16(vf1[dt].f, pf1.f, o[dt], 0, 0, 0);
    }

    l += __shfl_xor(l, 16);
    l += __shfl_xor(l, 32);
    float inv = 1.f / l;
#pragma unroll
    for (int dt = 0; dt < 4; dt++) {
        uint2 dw;
        dw.x = pkbf16(o[dt][0] * inv, o[dt][1] * inv);
        dw.y = pkbf16(o[dt][2] * inv, o[dt][3] * inv);
        *(uint2*)&O[qrow + dt * 16 + quad * 4] = dw;
    }
}

// ---------------------------------------------------------------------------
extern "C" void kernel_launch(void* const* d_in, const int* in_sizes, int n_in,
                              void* d_out, int out_size, void* d_ws, size_t ws_size,
                              hipStream_t stream) {
    (void)in_sizes; (void)n_in; (void)out_size; (void)ws_size;
    const float* query     = (const float*)d_in[0];
    const float* key_value = (const float*)d_in[1];
    const float* Wq = (const float*)d_in[2];
    const float* bq = (const float*)d_in[3];
    const float* Wk = (const float*)d_in[4];
    const float* bk = (const float*)d_in[5];
    const float* Wv = (const float*)d_in[6];
    const float* bv = (const float*)d_in[7];
    const float* Wo = (const float*)d_in[8];
    const float* bo = (const float*)d_in[9];
    const float* g1 = (const float*)d_in[10];
    const float* b1 = (const float*)d_in[11];
    const float* g2 = (const float*)d_in[12];
    const float* b2 = (const float*)d_in[13];
    const float* gate_up = (const float*)d_in[14];
    const float* down    = (const float*)d_in[15];
    float* out = (float*)d_out;

    char* wsb = (char*)d_ws;
    size_t off = 0;
    auto alloc = [&](size_t bytes) {
        char* p = wsb + off;
        off += (bytes + 255) & ~(size_t)255;
        return (void*)p;
    };
    u16* buf8a = (u16*)alloc((size_t)4096 * 1024 * 2);      // xn / ctx / hp
    u16* qb    = (u16*)alloc((size_t)4096 * 1024 * 2);
    u16* kvb   = (u16*)alloc((size_t)8192 * 1024 * 2);      // K proj out [b][key][1024]
    u16* vtb   = (u16*)alloc((size_t)8192 * 1024 * 2);      // V pi-fragment layout
    u16* kvbf  = (u16*)alloc((size_t)8192 * 1024 * 2);      // bf16 key_value; later inter
    float* x2  = (float*)alloc((size_t)4096 * 1024 * 4);
    u16* wqt   = (u16*)alloc((size_t)1024 * 1024 * 2);
    u16* kvw   = (u16*)alloc((size_t)2048 * 1024 * 2);      // Wk^T | Wv^T stacked
    u16* wot   = (u16*)alloc((size_t)1024 * 1024 * 2);
    u16* gut   = (u16*)alloc((size_t)4 * 2048 * 1024 * 2);  // permuted gate/up
    u16* dnt   = (u16*)alloc((size_t)4 * 1024 * 1024 * 2);
    u16* xn = buf8a; u16* ctx = buf8a; u16* hp = buf8a;
    u16* inter = kvbf;  // kvbf dead after KV projection
    const int BIG = 1 << 30;
    const float QSCALE = 0.125f * 1.44269504f;  // fold 1/sqrt(d) and log2(e)

    // all prep (weight transcasts + kv cast + LN1) in one launch
    prep_kernel<<<12288, 256, 0, stream>>>(
        Wq, Wk, Wv, Wo, wqt, kvw, kvw + (size_t)1024 * 1024, wot,
        gate_up, gut, down, dnt, key_value, kvbf, query, g1, b1, xn);
    // Q proj + KV proj merged (Q pre-scaled for exp2 softmax; KV mode 3)
    gemm_qkv<<<1536, 256, 32768, stream>>>(xn, wqt, bq, kvbf, kvw, bk, bv,
                                           qb, kvb, vtb, QSCALE);
    flash_attn<<<512, 512, 0, stream>>>(qb, kvb, vtb, ctx);
    // x2 = query + ctx@Wo + bo
    gemm_t<64><<<dim3(8, 64, 1), 256, 24576, stream>>>(ctx, wot, bo, bo, BIG,
        query, x2, nullptr, nullptr, 1024, 1024, 0, 0, 0, 0, 1.f);
    ln_kernel<<<4096, 256, 0, stream>>>(x2, g2, b2, hp, 1);
    // MoE gate_up + fused SiLU
    gemm_t<64><<<dim3(16, 16, 4), 256, 24576, stream>>>(hp, gut, nullptr, nullptr, BIG,
        nullptr, nullptr, inter, nullptr, 2048, 1024,
        (long long)1024 * 1024, (long long)2048 * 1024, (long long)1024 * 1024, 2, 1.f);
    // down-proj + residual + unscatter -> d_out
    gemm_t<64><<<dim3(8, 16, 4), 256, 24576, stream>>>(inter, dnt, nullptr, nullptr, BIG,
        x2, out, nullptr, nullptr, 1024, 1024,
        (long long)1024 * 1024, (long long)1024 * 1024, 0, 1, 1.f);
}

// Round 7
// 349.815 us; speedup vs baseline: 1.1248x; 1.0623x over previous
//
#include <hip/hip_runtime.h>
#include <hip/hip_bf16.h>

typedef unsigned short u16;
typedef float f32x4 __attribute__((ext_vector_type(4)));
typedef short s16x8 __attribute__((ext_vector_type(8)));

__device__ __forceinline__ u16 f2b(float f) {
    union { float f; unsigned u; } c; c.f = f;
    unsigned r = c.u + 0x7fffu + ((c.u >> 16) & 1u);
    return (u16)(r >> 16);
}
// packed f32x2 -> bf16x2 (v_cvt_pk_bf16_f32 on gfx950); low16 = a, high16 = b
__device__ __forceinline__ unsigned pkbf16(float a, float b) {
    union { __hip_bfloat162 h; unsigned u; } c;
    c.h = __float22bfloat162_rn(float2{a, b});
    return c.u;
}

// async global->LDS, 16B per lane; LDS dst = base + lane*16 (wave-uniform base)
#define ASYNC_COPY16(gp, lp)                                                       \
    __builtin_amdgcn_global_load_lds(                                              \
        (const __attribute__((address_space(1))) void*)(gp),                       \
        (__attribute__((address_space(3))) void*)(lp), 16, 0, 0)

// ---------------------------------------------------------------------------
// Weight cast+transpose body: W (K x N) f32 -> Wt (N x K) bf16, 64x64 tile.
// permute=1 interleaves gate/up channel rows (for fused-silu epilogue).
// ---------------------------------------------------------------------------
__device__ __forceinline__ void transcast_body(const float* __restrict__ Wz,
                                               u16* __restrict__ Wtz,
                                               int K, int N, int bx, int by,
                                               int permute) {
    __shared__ float tile[64][65];
    const int n0 = bx * 64, k0 = by * 64;
    const int tid = threadIdx.x;
    const int tx = tid & 15, ty = tid >> 4;
#pragma unroll
    for (int it = 0; it < 4; it++) {
        int r = ty + it * 16;
        float4 v = *(const float4*)&Wz[(size_t)(k0 + r) * N + n0 + tx * 4];
        tile[r][tx * 4 + 0] = v.x;
        tile[r][tx * 4 + 1] = v.y;
        tile[r][tx * 4 + 2] = v.z;
        tile[r][tx * 4 + 3] = v.w;
    }
    __syncthreads();
    int n = tid >> 2;
    int ks = (tid & 3) * 16;
    int drow = n0 + n;
    if (permute) drow = (drow < 1024) ? 2 * drow : 2 * (drow - 1024) + 1;
    u16* dst = &Wtz[(size_t)drow * K + k0 + ks];
#pragma unroll
    for (int h = 0; h < 2; h++) {
        uint4 o;
        o.x = pkbf16(tile[ks + h * 8 + 0][n], tile[ks + h * 8 + 1][n]);
        o.y = pkbf16(tile[ks + h * 8 + 2][n], tile[ks + h * 8 + 3][n]);
        o.z = pkbf16(tile[ks + h * 8 + 4][n], tile[ks + h * 8 + 5][n]);
        o.w = pkbf16(tile[ks + h * 8 + 6][n], tile[ks + h * 8 + 7][n]);
        *(uint4*)(dst + h * 8) = o;
    }
}

// f32 -> bf16 cast body, 8 elems/thread, one block-slice
__device__ __forceinline__ void cast_body(const float* __restrict__ x,
                                          u16* __restrict__ y, int blk) {
    int id = blk * 256 + threadIdx.x;
    const float* p = x + (size_t)id * 8;
    float4 a = *(const float4*)p;
    float4 b = *(const float4*)(p + 4);
    uint4 o;
    o.x = pkbf16(a.x, a.y);
    o.y = pkbf16(a.z, a.w);
    o.z = pkbf16(b.x, b.y);
    o.w = pkbf16(b.z, b.w);
    *(uint4*)(y + (size_t)id * 8) = o;
}

// LayerNorm body over H=1024; pack=1: MoE expert-packed row order
__device__ __forceinline__ void ln_body(const float* __restrict__ x,
                                        const float* __restrict__ g,
                                        const float* __restrict__ bb,
                                        u16* __restrict__ out, int token, int pack) {
    int tid = threadIdx.x;
    const float* row = x + (size_t)token * 1024;
    float4 v = *(const float4*)(row + tid * 4);
    float s1 = v.x + v.y + v.z + v.w;
    float s2 = v.x * v.x + v.y * v.y + v.z * v.z + v.w * v.w;
#pragma unroll
    for (int off = 32; off > 0; off >>= 1) {
        s1 += __shfl_down(s1, off);
        s2 += __shfl_down(s2, off);
    }
    __shared__ float ws1[4], ws2[4];
    int wave = tid >> 6;
    if ((tid & 63) == 0) { ws1[wave] = s1; ws2[wave] = s2; }
    __syncthreads();
    float t1 = ws1[0] + ws1[1] + ws1[2] + ws1[3];
    float t2 = ws2[0] + ws2[1] + ws2[2] + ws2[3];
    float mean = t1 * (1.f / 1024.f);
    float var = t2 * (1.f / 1024.f) - mean * mean;
    float rstd = rsqrtf(var + 1e-6f);
    size_t dest = token;
    if (pack) {
        int bq = token >> 10, q = token & 1023;
        dest = (size_t)(q & 3) * 1024 + (size_t)bq * 256 + (q >> 2);
    }
    int c = tid * 4;
    float4 gv = *(const float4*)(g + c);
    float4 bv = *(const float4*)(bb + c);
    uint2 o;
    o.x = pkbf16((v.x - mean) * rstd * gv.x + bv.x, (v.y - mean) * rstd * gv.y + bv.y);
    o.y = pkbf16((v.z - mean) * rstd * gv.z + bv.z, (v.w - mean) * rstd * gv.w + bv.w);
    *(uint2*)&out[dest * 1024 + c] = o;
}

__global__ __launch_bounds__(256) void ln_kernel(const float* __restrict__ x,
                                                 const float* __restrict__ g,
                                                 const float* __restrict__ bb,
                                                 u16* __restrict__ out, int pack) {
    ln_body(x, g, bb, out, blockIdx.x, pack);
}

// ---------------------------------------------------------------------------
// Mega prep kernel: all input-independent prep in ONE launch (was 5 launches —
// same-stream kernels serialize fully, so each separate launch paid ramp+tail).
// Block ranges: [0,1024) 4 square-weight transcasts; [1024,3072) gate_up
// transcast (permuted); [3072,4096) down transcast; [4096,8192) kv f32->bf16
// cast; [8192,12288) LN1.
// ---------------------------------------------------------------------------
__global__ __launch_bounds__(256) void prep_kernel(
    const float* __restrict__ Wq, const float* __restrict__ Wk,
    const float* __restrict__ Wv, const float* __restrict__ Wo,
    u16* __restrict__ wqt, u16* __restrict__ wkt,
    u16* __restrict__ wvt, u16* __restrict__ wot,
    const float* __restrict__ gate_up, u16* __restrict__ gut,
    const float* __restrict__ down, u16* __restrict__ dnt,
    const float* __restrict__ key_value, u16* __restrict__ kvbf,
    const float* __restrict__ query, const float* __restrict__ g1,
    const float* __restrict__ b1, u16* __restrict__ xn) {
    const int idx = blockIdx.x;
    if (idx < 1024) {
        int z = idx >> 8, r = idx & 255;
        const float* W = (z == 0) ? Wq : (z == 1) ? Wk : (z == 2) ? Wv : Wo;
        u16* O = (z == 0) ? wqt : (z == 1) ? wkt : (z == 2) ? wvt : wot;
        transcast_body(W, O, 1024, 1024, r >> 4, r & 15, 0);
    } else if (idx < 3072) {
        int t = idx - 1024, z = t >> 9, r = t & 511;
        transcast_body(gate_up + (size_t)z * 2097152, gut + (size_t)z * 2097152,
                       1024, 2048, r >> 4, r & 15, 1);
    } else if (idx < 4096) {
        int t = idx - 3072, z = t >> 8, r = t & 255;
        transcast_body(down + (size_t)z * 1048576, dnt + (size_t)z * 1048576,
                       1024, 1024, r >> 4, r & 15, 0);
    } else if (idx < 8192) {
        cast_body(key_value, kvbf, idx - 4096);
    } else {
        ln_body(query, g1, b1, xn, idx - 8192, 0);
    }
}

// ---------------------------------------------------------------------------
// bf16 MFMA GEMM body. R17: double-buffered LDS, ONE barrier per K-step
// (flash-proven T3 minimum-2-phase: stage(k+1) issued BEFORE compute(k), so
// the barrier's vmcnt(0) drain lands after a full compute phase instead of
// stalling cold — the single-buffer version spent ~34% of cycles in that
// drain: MfmaUtil 28 + VALUBusy 38 = 66% busy at R6). LDS: BM=128 -> 64 KB,
// BM=64 -> 48 KB. mode: 0=normal (outF+resid | outH*outScale), 1=MoE scatter
// f32+resid, 2=silu-pair -> outH (N/2 ch), 3=K normal + V in flash
// pi-fragment layout (outH2).
// ---------------------------------------------------------------------------
template <int BM>
__device__ __forceinline__ void gemm_body(
    u16* lds,
    const u16* __restrict__ Ab, const u16* __restrict__ Bb,
    const float* __restrict__ bias0, const float* __restrict__ bias1, int biasSplit,
    const float* __restrict__ resid,
    float* __restrict__ outF, u16* __restrict__ outH, u16* __restrict__ outH2,
    int N, int K, long long oStride, int z, int mode, float outScale,
    int m0, int n0) {
    constexpr int NJ = (BM == 128) ? 4 : 2;
    constexpr int HALF = BM * 64 + 128 * 64;   // u16 per buffer (A tile + B tile)
    const int tid = threadIdx.x;
    const int wave = tid >> 6, lane = tid & 63;
    const int wm = (BM == 128) ? (wave >> 1) * 64 : 0;
    const int wn = (BM == 128) ? (wave & 1) * 64 : wave * 32;
    const int quad = lane >> 4, l16 = lane & 15;
    f32x4 acc[4][NJ] = {};

    auto stage = [&](int k0, int buf) {
        u16* As = lds + buf * HALF;
        u16* Bs = As + BM * 64;
#pragma unroll
        for (int i = 0; i < BM / 32; i++) {
            int id = tid + i * 256;
            int row = id >> 3, c = id & 7;
            int srcseg = c ^ (row & 7);
            ASYNC_COPY16(&Ab[(size_t)(m0 + row) * K + k0 + srcseg * 8],
                         As + (size_t)(wave * 64 + i * 256) * 8);
        }
#pragma unroll
        for (int i = 0; i < 4; i++) {
            int id = tid + i * 256;
            int row = id >> 3, c = id & 7;
            int srcseg = c ^ (row & 7);
            ASYNC_COPY16(&Bb[(size_t)(n0 + row) * K + k0 + srcseg * 8],
                         Bs + (size_t)(wave * 64 + i * 256) * 8);
        }
    };

    stage(0, 0);
    int cur = 0;
    for (int k0 = 0; k0 < K; k0 += 64) {
        __syncthreads();                 // stage(k0) landed; other buf free
        if (k0 + 64 < K) stage(k0 + 64, cur ^ 1);
        const u16* As = lds + cur * HALF;
        const u16* Bs = As + BM * 64;
#pragma unroll
        for (int kk = 0; kk < 2; kk++) {
            s16x8 af[4], bfr[NJ];
#pragma unroll
            for (int i = 0; i < 4; i++) {
                int row = wm + i * 16 + l16;
                af[i] = *(const s16x8*)&As[row * 64 + ((kk * 4 + quad) ^ (row & 7)) * 8];
            }
#pragma unroll
            for (int j = 0; j < NJ; j++) {
                int row = wn + j * 16 + l16;
                bfr[j] = *(const s16x8*)&Bs[row * 64 + ((kk * 4 + quad) ^ (row & 7)) * 8];
            }
#pragma unroll
            for (int i = 0; i < 4; i++)
#pragma unroll
                for (int j = 0; j < NJ; j++)
                    acc[i][j] = __builtin_amdgcn_mfma_f32_16x16x32_bf16(af[i], bfr[j], acc[i][j], 0, 0, 0);
        }
        cur ^= 1;
    }
#pragma unroll
    for (int i = 0; i < 4; i++) {
#pragma unroll
        for (int j = 0; j < NJ; j++) {
            int col = n0 + wn + j * 16 + l16;
            float bv = 0.f;
            if (bias0) bv = (col < biasSplit) ? bias0[col] : bias1[col - biasSplit];
            if (mode == 3) {
                float vr[4];
#pragma unroll
                for (int r = 0; r < 4; r++) vr[r] = acc[i][j][r] + bv;
                int row0 = m0 + wm + i * 16 + quad * 4;
                if (col < 1024) {
#pragma unroll
                    for (int r = 0; r < 4; r++)
                        outH[(size_t)(row0 + r) * 1024 + col] = f2b(vr[r]);
                } else {
                    // flash pi-fragment scatter: key kk within chunk cc lands at
                    // seg = ((kk4>>1)*4 + q4) ^ (d&7), half = kk4&1
                    int bb2 = row0 >> 11, key = row0 & 2047;
                    int hh = (col - 1024) >> 6, d = (col - 1024) & 63;
                    int cc = key >> 6, kk = key & 63;
                    int kk4 = kk >> 4, q4 = (kk >> 2) & 3;
                    int seg = (((kk4 >> 1) << 2) | q4) ^ (d & 7);
                    int half = kk4 & 1;
                    uint2 dw;
                    dw.x = pkbf16(vr[0], vr[1]);
                    dw.y = pkbf16(vr[2], vr[3]);
                    *(uint2*)&outH2[((((size_t)bb2 * 16 + hh) * 32 + cc) * 64 + d) * 64
                                    + seg * 8 + half * 4] = dw;
                }
                continue;
            }
#pragma unroll
            for (int r = 0; r < 4; r++) {
                int row = m0 + wm + i * 16 + quad * 4 + r;
                float v = acc[i][j][r] + bv;
                if (mode == 2) {
                    float other = __shfl_xor(v, 1);
                    if (!(lane & 1)) {
                        float res = (v / (1.f + __expf(-v))) * other;
                        outH[(size_t)z * oStride + (size_t)row * (N >> 1) + (col >> 1)] = f2b(res);
                    }
                } else if (mode == 1) {
                    int bb2 = row >> 8, qi = row & 255;
                    size_t oidx = ((size_t)bb2 * 1024 + (size_t)z + 4 * (size_t)qi) * N + col;
                    outF[oidx] = v + resid[oidx];
                } else {
                    size_t oidx = (size_t)z * oStride + (size_t)row * N + col;
                    if (resid) v += resid[oidx];
                    if (outF) outF[oidx] = v;
                    else outH[oidx] = f2b(v * outScale);
                }
            }
        }
    }
}

// standalone GEMM wrapper (3-D grid, hardware dispatch order — R5 lesson)
template <int BM>
__global__ __launch_bounds__(256) void gemm_t(
    const u16* __restrict__ A, const u16* __restrict__ Bt,
    const float* __restrict__ bias0, const float* __restrict__ bias1, int biasSplit,
    const float* __restrict__ resid,
    float* __restrict__ outF, u16* __restrict__ outH, u16* __restrict__ outH2,
    int N, int K,
    long long aStride, long long bStride, long long oStride,
    int mode, float outScale) {
    extern __shared__ __align__(16) u16 ldsb[];
    const int z = blockIdx.z;
    gemm_body<BM>(ldsb,
                  A + (size_t)z * aStride, Bt + (size_t)z * bStride,
                  bias0, bias1, biasSplit, resid, outF, outH, outH2,
                  N, K, oStride, z, mode, outScale,
                  blockIdx.y * BM, blockIdx.x * 128);
}

// ---------------------------------------------------------------------------
// Merged Q-proj + KV-proj. R14: XCD-aware logical remap — each XCD (bid&7)
// owns 8 consecutive by-panels so A-panels stay resident in one L2 (FETCH
// 106 -> 55 MB). KV blocks first (heavier). Needs 64 KB dynamic LDS (dbuf).
// ---------------------------------------------------------------------------
__global__ __launch_bounds__(256) void gemm_qkv(
    const u16* __restrict__ xn, const u16* __restrict__ wqt,
    const float* __restrict__ bq,
    const u16* __restrict__ kvbf, const u16* __restrict__ kvw,
    const float* __restrict__ bk, const float* __restrict__ bv,
    u16* __restrict__ qb, u16* __restrict__ kvb, u16* __restrict__ vtb,
    float qscale) {
    extern __shared__ __align__(16) u16 ldsb[];
    const int bid = blockIdx.x;
    if (bid < 1024) {           // KV: xcd owns by in [xcd*8, xcd*8+8)
        int xcd = bid & 7, slot = bid >> 3;
        int by = xcd * 8 + (slot >> 4), bx = slot & 15;
        gemm_body<128>(ldsb, kvbf, kvw,
                       bk, bv, 1024, nullptr, nullptr, kvb, vtb,
                       2048, 1024, 0, 0, 3, 1.f,
                       by * 128, bx * 128);
    } else {                    // Q: xcd owns by in [xcd*8, xcd*8+8)
        int t = bid - 1024;
        int xcd = t & 7, slot = t >> 3;
        int by = xcd * 8 + (slot >> 3), bx = slot & 7;
        gemm_body<64>(ldsb, xn, wqt,
                      bq, bq, 1 << 30, nullptr, nullptr, qb, nullptr,
                      1024, 1024, 0, 0, 0, qscale,
                      by * 64, bx * 128);
    }
}

// ---------------------------------------------------------------------------
// Flash attention v11 (R16 best): 8-wave blocks, 16 q/wave, dbuf LDS, one
// barrier/chunk, V staged linearly from pre-permuted VT, P->PV in registers,
// bare v_exp_f32 softmax (exp2f's OCML guard code was ~5x VALU expansion —
// R16: 74.7 -> <60 us), c2=0 V-fragments preloaded under softmax.
// ---------------------------------------------------------------------------
__global__ __launch_bounds__(512, 4) void flash_attn(
    const u16* __restrict__ Q, const u16* __restrict__ Kb,
    const u16* __restrict__ VT, u16* __restrict__ O) {
    const int lidx = blockIdx.x;               // 512 blocks
    const int xcd = lidx & 7, slot = lidx >> 3;
    const int g = xcd + 8 * (slot >> 3);       // (b,h) group, 0..63
    const int qt = slot & 7;
    const int b = g >> 4, h = g & 15;
    const int tid = threadIdx.x, wave = tid >> 6, lane = tid & 63;
    const int quad = lane >> 4, l16 = lane & 15;
    const int q0 = qt * 128 + wave * 16;

    __shared__ __align__(16) u16 Ks[2][64 * 64];   // [key][d], 8-seg swz
    __shared__ __align__(16) u16 Vs[2][64 * 64];   // [d][pi(key)], 8-seg swz

    const size_t qrow = ((size_t)b * 1024 + q0 + l16) * 1024 + (size_t)h * 64;
    s16x8 qf0 = *(const s16x8*)&Q[qrow + quad * 8];
    s16x8 qf1 = *(const s16x8*)&Q[qrow + 32 + quad * 8];

    f32x4 o[4] = {};
    float l = 0.f;

    // ---- loop-invariant LDS uint4-indices (row&7 == l16&7 for all rows) ----
    const int l7 = l16 & 7;
    int koff[4][2], voff[2][4];
#pragma unroll
    for (int kt = 0; kt < 4; kt++) {
        koff[kt][0] = (kt * 16 + l16) * 8 + (quad ^ l7);
        koff[kt][1] = (kt * 16 + l16) * 8 + ((4 + quad) ^ l7);
    }
#pragma unroll
    for (int c2 = 0; c2 < 2; c2++)
#pragma unroll
        for (int dt = 0; dt < 4; dt++)
            voff[c2][dt] = (dt * 16 + l16) * 8 + ((c2 * 4 + quad) ^ l7);

    // ---- running staging pointers (one add per chunk, no c-multiplies) ----
    const int krow = tid >> 3;                 // key within chunk
    const int ksrcseg = (tid & 7) ^ (krow & 7);
    const u16* kSrc = Kb + ((size_t)b * 2048) * 1024 + (size_t)h * 64
                        + (size_t)krow * 1024 + ksrcseg * 8;
    const u16* vSrc = VT + ((size_t)(b * 16 + h) * 32) * 4096 + (size_t)tid * 8;
    u16* const kDst0 = &Ks[0][(size_t)(wave * 64) * 8];
    u16* const kDst1 = &Ks[1][(size_t)(wave * 64) * 8];
    u16* const vDst0 = &Vs[0][(size_t)(wave * 64) * 8];
    u16* const vDst1 = &Vs[1][(size_t)(wave * 64) * 8];

    ASYNC_COPY16(kSrc, kDst0);
    ASYNC_COPY16(vSrc, vDst0);
    kSrc += 64 * 1024; vSrc += 4096;

    for (int c = 0; c < 32; c++) {
        __syncthreads();                        // stage(c) landed; other buf free
        if (c < 31) {                           // prefetch next chunk
            if (c & 1) { ASYNC_COPY16(kSrc, kDst0); ASYNC_COPY16(vSrc, vDst0); }
            else       { ASYNC_COPY16(kSrc, kDst1); ASYNC_COPY16(vSrc, vDst1); }
            kSrc += 64 * 1024; vSrc += 4096;
        }
        const uint4* Kp = (const uint4*)((c & 1) ? &Ks[1][0] : &Ks[0][0]);
        const uint4* Vp = (const uint4*)((c & 1) ? &Vs[1][0] : &Vs[0][0]);

        f32x4 s[4];
#pragma unroll
        for (int kt = 0; kt < 4; kt++) {
            union { uint4 v; s16x8 f; } a0, a1;
            a0.v = Kp[koff[kt][0]];
            a1.v = Kp[koff[kt][1]];
            f32x4 acc = {};
            acc = __builtin_amdgcn_mfma_f32_16x16x32_bf16(a0.f, qf0, acc, 0, 0, 0);
            s[kt] = __builtin_amdgcn_mfma_f32_16x16x32_bf16(a1.f, qf1, acc, 0, 0, 0);
        }

        // preload c2=0 V-fragments; LDS latency overlaps the softmax below
        union { uint4 v; s16x8 f; } vf0[4];
#pragma unroll
        for (int dt = 0; dt < 4; dt++) vf0[dt].v = Vp[voff[0][dt]];

        uint2 dw[4];
        float rs = 0.f;
#pragma unroll
        for (int kt = 0; kt < 4; kt++) {
            float p0 = __builtin_amdgcn_exp2f(s[kt][0]);
            float p1 = __builtin_amdgcn_exp2f(s[kt][1]);
            float p2 = __builtin_amdgcn_exp2f(s[kt][2]);
            float p3 = __builtin_amdgcn_exp2f(s[kt][3]);
            rs += (p0 + p1) + (p2 + p3);
            dw[kt].x = pkbf16(p0, p1);
            dw[kt].y = pkbf16(p2, p3);
        }
        l += rs;

        // PV: c2=0 from preloaded regs, c2=1 inline (latency under c2=0 MFMAs)
        union { uint4 v; s16x8 f; } pf0, pf1;
        pf0.v = uint4{dw[0].x, dw[0].y, dw[1].x, dw[1].y};
        pf1.v = uint4{dw[2].x, dw[2].y, dw[3].x, dw[3].y};
        union { uint4 v; s16x8 f; } vf1[4];
#pragma unroll
        for (int dt = 0; dt < 4; dt++) vf1[dt].v = Vp[voff[1][dt]];
#pragma unroll
        for (int dt = 0; dt < 4; dt++)
            o[dt] = __builtin_amdgcn_mfma_f32_16x16x32_bf16(vf0[dt].f, pf0.f, o[dt], 0, 0, 0);
#pragma unroll
        for (int dt = 0; dt < 4; dt++)
            o[dt] = __builtin_amdgcn_mfma_f32_16x16x32_bf16(vf1[dt].f, pf1.f, o[dt], 0, 0, 0);
    }

    l += __shfl_xor(l, 16);
    l += __shfl_xor(l, 32);
    float inv = 1.f / l;
#pragma unroll
    for (int dt = 0; dt < 4; dt++) {
        uint2 dw;
        dw.x = pkbf16(o[dt][0] * inv, o[dt][1] * inv);
        dw.y = pkbf16(o[dt][2] * inv, o[dt][3] * inv);
        *(uint2*)&O[qrow + dt * 16 + quad * 4] = dw;
    }
}

// ---------------------------------------------------------------------------
extern "C" void kernel_launch(void* const* d_in, const int* in_sizes, int n_in,
                              void* d_out, int out_size, void* d_ws, size_t ws_size,
                              hipStream_t stream) {
    (void)in_sizes; (void)n_in; (void)out_size; (void)ws_size;
    const float* query     = (const float*)d_in[0];
    const float* key_value = (const float*)d_in[1];
    const float* Wq = (const float*)d_in[2];
    const float* bq = (const float*)d_in[3];
    const float* Wk = (const float*)d_in[4];
    const float* bk = (const float*)d_in[5];
    const float* Wv = (const float*)d_in[6];
    const float* bv = (const float*)d_in[7];
    const float* Wo = (const float*)d_in[8];
    const float* bo = (const float*)d_in[9];
    const float* g1 = (const float*)d_in[10];
    const float* b1 = (const float*)d_in[11];
    const float* g2 = (const float*)d_in[12];
    const float* b2 = (const float*)d_in[13];
    const float* gate_up = (const float*)d_in[14];
    const float* down    = (const float*)d_in[15];
    float* out = (float*)d_out;

    char* wsb = (char*)d_ws;
    size_t off = 0;
    auto alloc = [&](size_t bytes) {
        char* p = wsb + off;
        off += (bytes + 255) & ~(size_t)255;
        return (void*)p;
    };
    u16* buf8a = (u16*)alloc((size_t)4096 * 1024 * 2);      // xn / ctx / hp
    u16* qb    = (u16*)alloc((size_t)4096 * 1024 * 2);
    u16* kvb   = (u16*)alloc((size_t)8192 * 1024 * 2);      // K proj out [b][key][1024]
    u16* vtb   = (u16*)alloc((size_t)8192 * 1024 * 2);      // V pi-fragment layout
    u16* kvbf  = (u16*)alloc((size_t)8192 * 1024 * 2);      // bf16 key_value; later inter
    float* x2  = (float*)alloc((size_t)4096 * 1024 * 4);
    u16* wqt   = (u16*)alloc((size_t)1024 * 1024 * 2);
    u16* kvw   = (u16*)alloc((size_t)2048 * 1024 * 2);      // Wk^T | Wv^T stacked
    u16* wot   = (u16*)alloc((size_t)1024 * 1024 * 2);
    u16* gut   = (u16*)alloc((size_t)4 * 2048 * 1024 * 2);  // permuted gate/up
    u16* dnt   = (u16*)alloc((size_t)4 * 1024 * 1024 * 2);
    u16* xn = buf8a; u16* ctx = buf8a; u16* hp = buf8a;
    u16* inter = kvbf;  // kvbf dead after KV projection
    const int BIG = 1 << 30;
    const float QSCALE = 0.125f * 1.44269504f;  // fold 1/sqrt(d) and log2(e)

    // all prep (weight transcasts + kv cast + LN1) in one launch
    prep_kernel<<<12288, 256, 0, stream>>>(
        Wq, Wk, Wv, Wo, wqt, kvw, kvw + (size_t)1024 * 1024, wot,
        gate_up, gut, down, dnt, key_value, kvbf, query, g1, b1, xn);
    // Q proj + KV proj merged (Q pre-scaled for exp2 softmax; KV mode 3)
    gemm_qkv<<<1536, 256, 65536, stream>>>(xn, wqt, bq, kvbf, kvw, bk, bv,
                                           qb, kvb, vtb, QSCALE);
    flash_attn<<<512, 512, 0, stream>>>(qb, kvb, vtb, ctx);
    // x2 = query + ctx@Wo + bo
    gemm_t<64><<<dim3(8, 64, 1), 256, 49152, stream>>>(ctx, wot, bo, bo, BIG,
        query, x2, nullptr, nullptr, 1024, 1024, 0, 0, 0, 0, 1.f);
    ln_kernel<<<4096, 256, 0, stream>>>(x2, g2, b2, hp, 1);
    // MoE gate_up + fused SiLU
    gemm_t<64><<<dim3(16, 16, 4), 256, 49152, stream>>>(hp, gut, nullptr, nullptr, BIG,
        nullptr, nullptr, inter, nullptr, 2048, 1024,
        (long long)1024 * 1024, (long long)2048 * 1024, (long long)1024 * 1024, 2, 1.f);
    // down-proj + residual + unscatter -> d_out
    gemm_t<64><<<dim3(8, 16, 4), 256, 49152, stream>>>(inter, dnt, nullptr, nullptr, BIG,
        x2, out, nullptr, nullptr, 1024, 1024,
        (long long)1024 * 1024, (long long)1024 * 1024, 0, 1, 1.f);
}